// Round 7
// baseline (1918.479 us; speedup 1.0000x reference)
//
#include <hip/hip_runtime.h>
#include <hip/hip_bf16.h>

#define NS 512     // states
#define MS 256     // symbols
#define TB 256     // sequence length
#define NWG 16     // workgroups = batch groups (16 batches each)
#define BPG 16     // batches per group

// workspace byte offsets
#define OFF_LOGET  0u
#define OFF_LOGPRI 524288u
#define OFF_TEXP   526336u

typedef __attribute__((ext_vector_type(8))) short short8;
typedef __attribute__((ext_vector_type(4))) float f32x4;

__device__ __forceinline__ unsigned short bf_bits(float f) {
    __hip_bfloat16 h = __float2bfloat16(f);
    unsigned short u; __builtin_memcpy(&u, &h, 2); return u;
}

__global__ void k_emission(const float* __restrict__ E, float* __restrict__ logET) {
    int n = blockIdx.x;
    int lane = threadIdx.x;
    const float* row = E + (size_t)n * MS;
    float v[4]; float mx = -1e30f;
#pragma unroll
    for (int j = 0; j < 4; ++j) { v[j] = row[lane + 64 * j]; mx = fmaxf(mx, v[j]); }
#pragma unroll
    for (int off = 1; off < 64; off <<= 1) mx = fmaxf(mx, __shfl_xor(mx, off));
    float s = 0.f;
#pragma unroll
    for (int j = 0; j < 4; ++j) s += __expf(v[j] - mx);
#pragma unroll
    for (int off = 1; off < 64; off <<= 1) s += __shfl_xor(s, off);
    float lse = mx + __logf(s);
#pragma unroll
    for (int j = 0; j < 4; ++j) logET[(size_t)(lane + 64 * j) * NS + n] = v[j] - lse;
}

__global__ void k_transition(const float* __restrict__ U, __hip_bfloat16* __restrict__ Texp) {
    int k = blockIdx.x;
    int lane = threadIdx.x;
    float v[8]; float mx = -1e30f;
#pragma unroll
    for (int j = 0; j < 8; ++j) { v[j] = U[(size_t)(lane + 64 * j) * NS + k]; mx = fmaxf(mx, v[j]); }
#pragma unroll
    for (int off = 1; off < 64; off <<= 1) mx = fmaxf(mx, __shfl_xor(mx, off));
    float s = 0.f;
#pragma unroll
    for (int j = 0; j < 8; ++j) s += __expf(v[j] - mx);
#pragma unroll
    for (int off = 1; off < 64; off <<= 1) s += __shfl_xor(s, off);
    float lse = mx + __logf(s);
#pragma unroll
    for (int j = 0; j < 8; ++j)
        Texp[(size_t)(lane + 64 * j) * NS + k] = __float2bfloat16(__expf(v[j] - lse));
}

__global__ void k_priors(const float* __restrict__ U, float* __restrict__ lp) {
    int lane = threadIdx.x;
    float v[8]; float mx = -1e30f;
#pragma unroll
    for (int j = 0; j < 8; ++j) { v[j] = U[lane + 64 * j]; mx = fmaxf(mx, v[j]); }
#pragma unroll
    for (int off = 1; off < 64; off <<= 1) mx = fmaxf(mx, __shfl_xor(mx, off));
    float s = 0.f;
#pragma unroll
    for (int j = 0; j < 8; ++j) s += __expf(v[j] - mx);
#pragma unroll
    for (int off = 1; off < 64; off <<= 1) s += __shfl_xor(s, off);
    float lse = mx + __logf(s);
#pragma unroll
    for (int j = 0; j < 8; ++j) lp[lane + 64 * j] = v[j] - lse;
}

// 16 WGs x 1024 threads. WG g owns batches [g*16,(g+1)*16) AND all 512 states:
// no inter-WG communication at all. Wave w owns output states [w*32,(w+1)*32).
// alpha lives in an LDS double-buffer [2][16][512] bf16 (chunk-XOR swizzled);
// B-operand (Texp rows) streams from per-XCD L2 each step (addresses constant).
// Normalization deferred one step: stored ap(t) = P_raw(t)*exp(em_t)/q(t-1);
// since T columns sum to 1, rowsum(P_raw(t)) = q(t-1), so stored values stay
// O(exp(em)) ~ 1e-2 .. 1e-3 (bf16-safe, no drift). out[b,t] = sum_{u<=t} log q(u).
__launch_bounds__(1024, 4)
__global__ void k_forward(const int* __restrict__ batch, const float* __restrict__ logET,
                          const __hip_bfloat16* __restrict__ Texp,
                          const float* __restrict__ logpri,
                          float* __restrict__ out) {
    __shared__ __align__(16) __hip_bfloat16 Ab[2][BPG][NS];  // 32 KB, chunk^row swizzle
    __shared__ int syms[BPG * TB];                           // 16 KB
    __shared__ float qred[16][BPG];                          // [wave][batch]
    __shared__ float qinv_s[BPG];

    const int tid = threadIdx.x;
    const int lane = tid & 63;
    const int w = tid >> 6;       // wave 0..15 -> states [w*32, w*32+32)
    const int hi = lane >> 4;     // 0..3
    const int lo = lane & 15;
    const int g = blockIdx.x;
    const int b0 = g * BPG;

    for (int idx = tid; idx < BPG * TB; idx += 1024)
        syms[idx] = batch[b0 * TB + idx];
    __syncthreads();

    float nrm = 0.f;   // maintained by tid<16 only (batch b0+tid)

    // ---- prologue t=0: ap0 = exp(em0 + priors), rowsum = q(0) ----
    {
        float ap[4][2];
#pragma unroll
        for (int r = 0; r < 4; ++r) {
            int b = hi * 4 + r;
            int sym = syms[b * TB];
#pragma unroll
            for (int nt = 0; nt < 2; ++nt) {
                int i = w * 32 + nt * 16 + lo;
                ap[r][nt] = __expf(logET[(size_t)sym * NS + i] + logpri[i]);
            }
        }
        // store A(0) (parity 0) with chunk^row swizzle + wave-local q partials
#pragma unroll
        for (int r = 0; r < 4; ++r) {
            int b = hi * 4 + r;
#pragma unroll
            for (int nt = 0; nt < 2; ++nt) {
                int col = w * 32 + nt * 16 + lo;
                int phys = (col >> 3) ^ b;
                *reinterpret_cast<unsigned short*>(
                    reinterpret_cast<char*>(&Ab[0][b][0]) + phys * 16 + (col & 7) * 2) =
                    bf_bits(ap[r][nt]);
            }
        }
        float p[4];
#pragma unroll
        for (int r = 0; r < 4; ++r) p[r] = ap[r][0] + ap[r][1];
#pragma unroll
        for (int off = 1; off < 16; off <<= 1)
#pragma unroll
            for (int r = 0; r < 4; ++r) p[r] += __shfl_xor(p[r], off);
        if (lo == 0)
#pragma unroll
            for (int r = 0; r < 4; ++r) qred[w][hi * 4 + r] = p[r];
        __syncthreads();
        if (tid < BPG) {
            float q = 0.f;
#pragma unroll
            for (int w2 = 0; w2 < 16; ++w2) q += qred[w2][tid];
            float lq = __logf(q);
            nrm = lq;
            out[(size_t)(b0 + tid) * TB] = lq;
            qinv_s[tid] = 1.0f / q;
        }
        __syncthreads();
    }

    // ---- main scan ----
    for (int t = 1; t < TB; ++t) {
        const int pr = (t - 1) & 1, pw = t & 1;

        // fac[r][nt] = exp(em_t) * qinv(t-1)   (reads qinv_s written last step)
        float fac[4][2];
#pragma unroll
        for (int r = 0; r < 4; ++r) {
            int b = hi * 4 + r;
            float qi = qinv_s[b];
            int sym = syms[b * TB + t];
#pragma unroll
            for (int nt = 0; nt < 2; ++nt)
                fac[r][nt] = __expf(logET[(size_t)sym * NS + w * 32 + nt * 16 + lo]) * qi;
        }

        // GEMM: P_raw[b, il] = sum_k A(t-1)[b,k] * T[il,k]; A from LDS, B from L2
        f32x4 acc0 = {}, acc1 = {};
        const __hip_bfloat16* T0 = Texp + (size_t)(w * 32 + lo) * NS;
        const __hip_bfloat16* T1 = T0 + 16 * NS;
        const char* Arow = reinterpret_cast<const char*>(&Ab[pr][0][0]) + lo * (NS * 2);
#pragma unroll
        for (int kb = 0; kb < 16; ++kb) {
            int phys = (kb * 4 + hi) ^ lo;
            short8 a = *reinterpret_cast<const short8*>(Arow + phys * 16);
            short8 bv0 = *reinterpret_cast<const short8*>(T0 + kb * 32 + hi * 8);
            short8 bv1 = *reinterpret_cast<const short8*>(T1 + kb * 32 + hi * 8);
            acc0 = __builtin_amdgcn_mfma_f32_16x16x32_bf16(a, bv0, acc0, 0, 0, 0);
            acc1 = __builtin_amdgcn_mfma_f32_16x16x32_bf16(a, bv1, acc1, 0, 0, 0);
        }

        // epilogue: ap(t) = acc * fac; store A(t); wave-local q partials
        float ap[4][2];
#pragma unroll
        for (int r = 0; r < 4; ++r) {
            ap[r][0] = acc0[r] * fac[r][0];
            ap[r][1] = acc1[r] * fac[r][1];
        }
#pragma unroll
        for (int r = 0; r < 4; ++r) {
            int b = hi * 4 + r;
#pragma unroll
            for (int nt = 0; nt < 2; ++nt) {
                int col = w * 32 + nt * 16 + lo;
                int phys = (col >> 3) ^ b;
                *reinterpret_cast<unsigned short*>(
                    reinterpret_cast<char*>(&Ab[pw][b][0]) + phys * 16 + (col & 7) * 2) =
                    bf_bits(ap[r][nt]);
            }
        }
        float p[4];
#pragma unroll
        for (int r = 0; r < 4; ++r) p[r] = ap[r][0] + ap[r][1];
#pragma unroll
        for (int off = 1; off < 16; off <<= 1)
#pragma unroll
            for (int r = 0; r < 4; ++r) p[r] += __shfl_xor(p[r], off);
        if (lo == 0)
#pragma unroll
            for (int r = 0; r < 4; ++r) qred[w][hi * 4 + r] = p[r];
        __syncthreads();   // bar1: A(t) + qred complete

        if (tid < BPG) {
            float q = 0.f;
#pragma unroll
            for (int w2 = 0; w2 < 16; ++w2) q += qred[w2][tid];
            float lq = __logf(q);
            nrm += lq;
            out[(size_t)(b0 + tid) * TB + t] = nrm;
            qinv_s[tid] = 1.0f / q;
        }
        __syncthreads();   // bar2: qinv ready; qred free for reuse
    }
}

extern "C" void kernel_launch(void* const* d_in, const int* in_sizes, int n_in,
                              void* d_out, int out_size, void* d_ws, size_t ws_size,
                              hipStream_t stream) {
    const int* batch = (const int*)d_in[0];
    const float* unE = (const float*)d_in[1];
    const float* unT = (const float*)d_in[2];
    const float* unP = (const float*)d_in[3];
    float* outp = (float*)d_out;

    char* ws = (char*)d_ws;
    float* logET = (float*)(ws + OFF_LOGET);
    float* logpri = (float*)(ws + OFF_LOGPRI);
    __hip_bfloat16* Texp = (__hip_bfloat16*)(ws + OFF_TEXP);

    k_emission<<<NS, 64, 0, stream>>>(unE, logET);
    k_transition<<<NS, 64, 0, stream>>>(unT, Texp);
    k_priors<<<1, 64, 0, stream>>>(unP, logpri);
    k_forward<<<NWG, 1024, 0, stream>>>(batch, logET, Texp, logpri, outp);
}

// Round 8
// 645.039 us; speedup vs baseline: 2.9742x; 2.9742x over previous
//
#include <hip/hip_runtime.h>
#include <hip/hip_bf16.h>

#define NS 512     // states
#define MS 256     // symbols
#define TB 256     // sequence length
#define NWG 16     // workgroups = batch groups
#define BPG 16     // batches per group

// workspace byte offsets
#define OFF_EEXP  0u          // f32 [256 sym][512 state]  = 512KB  (emission probs)
#define OFF_PEXP  524288u     // f32 [512]                 (prior probs)
#define OFF_TFRAG 526336u     // bf16 fragment-major [32 st][16 kb][64 lane][8] = 512KB

typedef __attribute__((ext_vector_type(8))) short short8;
typedef __attribute__((ext_vector_type(4))) float f32x4;

__device__ __forceinline__ unsigned short bf_bits(float f) {
    __hip_bfloat16 h = __float2bfloat16(f);
    unsigned short u; __builtin_memcpy(&u, &h, 2); return u;
}

// expET[m][n] = exp(log_softmax(E[n,:], over m))  -- block n, lanes over m
__global__ void k_emission(const float* __restrict__ E, float* __restrict__ expET) {
    int n = blockIdx.x;
    int lane = threadIdx.x;
    const float* row = E + (size_t)n * MS;
    float v[4]; float mx = -1e30f;
#pragma unroll
    for (int j = 0; j < 4; ++j) { v[j] = row[lane + 64 * j]; mx = fmaxf(mx, v[j]); }
#pragma unroll
    for (int off = 1; off < 64; off <<= 1) mx = fmaxf(mx, __shfl_xor(mx, off));
    float s = 0.f;
#pragma unroll
    for (int j = 0; j < 4; ++j) s += __expf(v[j] - mx);
#pragma unroll
    for (int off = 1; off < 64; off <<= 1) s += __shfl_xor(s, off);
    float lse = mx + __logf(s);
#pragma unroll
    for (int j = 0; j < 4; ++j)
        expET[(size_t)(lane + 64 * j) * NS + n] = __expf(v[j] - lse);
}

// T fragments, MFMA-lane-major: cell (st,kb) holds T[state=st*16+lo][k=kb*32+hk*8+j]
// at byte ((st*16+kb)<<10) + (hk*16+lo)*16 + j*2.  Column-softmax over i (dim 0).
__global__ void k_transition(const float* __restrict__ U, __hip_bfloat16* __restrict__ Tf) {
    int k = blockIdx.x;
    int lane = threadIdx.x;
    float v[8]; float mx = -1e30f;
#pragma unroll
    for (int j = 0; j < 8; ++j) { v[j] = U[(size_t)(lane + 64 * j) * NS + k]; mx = fmaxf(mx, v[j]); }
#pragma unroll
    for (int off = 1; off < 64; off <<= 1) mx = fmaxf(mx, __shfl_xor(mx, off));
    float s = 0.f;
#pragma unroll
    for (int j = 0; j < 8; ++j) s += __expf(v[j] - mx);
#pragma unroll
    for (int off = 1; off < 64; off <<= 1) s += __shfl_xor(s, off);
    float lse = mx + __logf(s);
    int kb = k >> 5, hk = (k >> 3) & 3, jj = k & 7;
#pragma unroll
    for (int j = 0; j < 8; ++j) {
        int i = lane + 64 * j;
        int st = i >> 4, li = i & 15;
        size_t byte = ((size_t)(st * 16 + kb) << 10) + (unsigned)(hk * 16 + li) * 16 + jj * 2;
        *reinterpret_cast<unsigned short*>(reinterpret_cast<char*>(Tf) + byte) =
            bf_bits(__expf(v[j] - lse));
    }
}

__global__ void k_priors(const float* __restrict__ U, float* __restrict__ pexp) {
    int lane = threadIdx.x;
    float v[8]; float mx = -1e30f;
#pragma unroll
    for (int j = 0; j < 8; ++j) { v[j] = U[lane + 64 * j]; mx = fmaxf(mx, v[j]); }
#pragma unroll
    for (int off = 1; off < 64; off <<= 1) mx = fmaxf(mx, __shfl_xor(mx, off));
    float s = 0.f;
#pragma unroll
    for (int j = 0; j < 8; ++j) s += __expf(v[j] - mx);
#pragma unroll
    for (int off = 1; off < 64; off <<= 1) s += __shfl_xor(s, off);
    float lse = mx + __logf(s);
#pragma unroll
    for (int j = 0; j < 8; ++j) pexp[lane + 64 * j] = __expf(v[j] - lse);
}

// 16 WGs x 512 threads (8 waves). WG owns 16 batches + all 512 states.
// Wave w owns output states [w*64,(w+1)*64) = 64 T-cells: cells c=kb*4+stL,
// c<49 pinned in VGPRs (196 regs), c>=49 in LDS (15KB/wave). alpha exchanged
// through an LDS fragment-major double-buffer; deferred normalization
// (rowsum(P_raw(t)) = q(t-1), T columns sum to 1) keeps values bf16-safe.
// out[b,t] = running sum of log q. Zero global traffic in the GEMM.
__launch_bounds__(512, 2)
__global__ void k_forward(const int* __restrict__ batch, const float* __restrict__ expET,
                          const __hip_bfloat16* __restrict__ Tf,
                          const float* __restrict__ pexp,
                          float* __restrict__ out) {
    __shared__ __align__(16) char Alds[2][16 * 1024];   // A frags per kb, lane-major (32KB)
    __shared__ __align__(16) char Tlds[8][15 * 1024];   // per-wave cells 49..63 (120KB)
    __shared__ float qred[8][BPG];
    __shared__ float qinv_s[BPG];

    const int tid = threadIdx.x;
    const int lane = tid & 63;
    const int w = tid >> 6;       // wave 0..7 -> states [w*64,(w+1)*64)
    const int hi = lane >> 4;
    const int lo = lane & 15;
    const int g = blockIdx.x;
    const int b0 = g * BPG;
    const char* TfC = reinterpret_cast<const char*>(Tf);

    // ---- stage 15 LDS-resident T cells (c = 49..63) ----
#pragma unroll
    for (int c = 49; c < 64; ++c) {
        const int kb = c >> 2, stL = c & 3, st = w * 4 + stL;
        short8 v = *reinterpret_cast<const short8*>(TfC + ((size_t)(st * 16 + kb) << 10) + lane * 16);
        *reinterpret_cast<short8*>(&Tlds[w][(c - 49) * 1024 + lane * 16]) = v;
    }

    // ---- t = 0: ap0 = Eexp[sym0]*pexp; write A(0) frags; q partials ----
    {
        int symr[4];
#pragma unroll
        for (int r = 0; r < 4; ++r) symr[r] = batch[(size_t)(b0 + hi * 4 + r) * TB];
        float p[4] = {0.f, 0.f, 0.f, 0.f};
#pragma unroll
        for (int stL = 0; stL < 4; ++stL) {
            int s = w * 64 + stL * 16 + lo;
            float pe = pexp[s];
            const int kbp = w * 2 + (stL >> 1);
            const int hip = (stL & 1) * 2 + (lo >> 3);
#pragma unroll
            for (int r = 0; r < 4; ++r) {
                float a = expET[(size_t)symr[r] * NS + s] * pe;
                p[r] += a;
                *reinterpret_cast<unsigned short*>(
                    &Alds[0][kbp * 1024 + (hip * 16 + hi * 4 + r) * 16 + (lo & 7) * 2]) = bf_bits(a);
            }
        }
#pragma unroll
        for (int off = 1; off < 16; off <<= 1)
#pragma unroll
            for (int r = 0; r < 4; ++r) p[r] += __shfl_xor(p[r], off);
        if (lo == 0)
#pragma unroll
            for (int r = 0; r < 4; ++r) qred[w][hi * 4 + r] = p[r];
    }
    __syncthreads();
    float nrm = 0.f;
    if (tid < BPG) {
        float q = 0.f;
#pragma unroll
        for (int w2 = 0; w2 < 8; ++w2) q += qred[w2][tid];
        float lq = __logf(q);
        nrm = lq;
        out[(size_t)(b0 + tid) * TB] = lq;
        qinv_s[tid] = 1.0f / q;
    }
    __syncthreads();

    // ---- pin 49 T cells (c = 0..48) in VGPRs: 196 regs ----
    short8 tf[49];
#pragma unroll
    for (int c = 0; c < 49; ++c) {
        const int kb = c >> 2, stL = c & 3, st = w * 4 + stL;
        tf[c] = *reinterpret_cast<const short8*>(TfC + ((size_t)(st * 16 + kb) << 10) + lane * 16);
    }

    // ---- main scan ----
    for (int t = 1; t < TB; ++t) {
        const int pr = (t - 1) & 1, pw = t & 1;

        // fac[stL][r] = Eexp[sym_t][s] * qinv(t-1)
        int symr[4];
#pragma unroll
        for (int r = 0; r < 4; ++r) symr[r] = batch[(size_t)(b0 + hi * 4 + r) * TB + t];
        float qi[4];
#pragma unroll
        for (int r = 0; r < 4; ++r) qi[r] = qinv_s[hi * 4 + r];
        float fac[4][4];
#pragma unroll
        for (int stL = 0; stL < 4; ++stL)
#pragma unroll
            for (int r = 0; r < 4; ++r)
                fac[stL][r] = expET[(size_t)symr[r] * NS + w * 64 + stL * 16 + lo] * qi[r];

        // GEMM: P_raw[b, s] = sum_k A(t-1)[b,k] * T[s,k] -- A from LDS, T from VGPR/LDS
        f32x4 acc[4] = {};
        const char* Ab = &Alds[pr][0];
#pragma unroll
        for (int kb = 0; kb < 16; ++kb) {
            short8 af = *reinterpret_cast<const short8*>(Ab + kb * 1024 + lane * 16);
#pragma unroll
            for (int stL = 0; stL < 4; ++stL) {
                const int c = kb * 4 + stL;
                short8 bf;
                if (c < 49) bf = tf[c];
                else bf = *reinterpret_cast<const short8*>(&Tlds[w][(c - 49) * 1024 + lane * 16]);
                acc[stL] = __builtin_amdgcn_mfma_f32_16x16x32_bf16(af, bf, acc[stL], 0, 0, 0);
            }
        }

        // epilogue: ap = acc * fac; write A(t) frags; q partials
        float p[4] = {0.f, 0.f, 0.f, 0.f};
#pragma unroll
        for (int stL = 0; stL < 4; ++stL) {
            const int kbp = w * 2 + (stL >> 1);
            const int hip = (stL & 1) * 2 + (lo >> 3);
#pragma unroll
            for (int r = 0; r < 4; ++r) {
                float a = acc[stL][r] * fac[stL][r];
                p[r] += a;
                *reinterpret_cast<unsigned short*>(
                    &Alds[pw][kbp * 1024 + (hip * 16 + hi * 4 + r) * 16 + (lo & 7) * 2]) = bf_bits(a);
            }
        }
#pragma unroll
        for (int off = 1; off < 16; off <<= 1)
#pragma unroll
            for (int r = 0; r < 4; ++r) p[r] += __shfl_xor(p[r], off);
        if (lo == 0)
#pragma unroll
            for (int r = 0; r < 4; ++r) qred[w][hi * 4 + r] = p[r];
        __syncthreads();   // bar1: A(t) + qred complete

        if (tid < BPG) {
            float q = 0.f;
#pragma unroll
            for (int w2 = 0; w2 < 8; ++w2) q += qred[w2][tid];
            float lq = __logf(q);
            nrm += lq;
            out[(size_t)(b0 + tid) * TB + t] = nrm;
            qinv_s[tid] = 1.0f / q;
        }
        __syncthreads();   // bar2: qinv ready
    }
}

extern "C" void kernel_launch(void* const* d_in, const int* in_sizes, int n_in,
                              void* d_out, int out_size, void* d_ws, size_t ws_size,
                              hipStream_t stream) {
    const int* batch = (const int*)d_in[0];
    const float* unE = (const float*)d_in[1];
    const float* unT = (const float*)d_in[2];
    const float* unP = (const float*)d_in[3];
    float* outp = (float*)d_out;

    char* ws = (char*)d_ws;
    float* expET = (float*)(ws + OFF_EEXP);
    float* pexp = (float*)(ws + OFF_PEXP);
    __hip_bfloat16* Tfrag = (__hip_bfloat16*)(ws + OFF_TFRAG);

    k_emission<<<NS, 64, 0, stream>>>(unE, expET);
    k_transition<<<NS, 64, 0, stream>>>(unT, Tfrag);
    k_priors<<<1, 64, 0, stream>>>(unP, pexp);
    k_forward<<<NWG, 512, 0, stream>>>(batch, expET, Tfrag, pexp, outp);
}